// Round 11
// baseline (535.011 us; speedup 1.0000x reference)
//
#include <hip/hip_runtime.h>
#include <hip/hip_bf16.h>

#define BSZ 16
#define Nn 96
#define HD 128
#define NDIM 3
#define HFEAT 6
#define FINC 7
#define BN (BSZ*Nn)

typedef const float* fp;
typedef __bf16 bf16x8_t __attribute__((ext_vector_type(8)));
typedef float  f32x4_t  __attribute__((ext_vector_type(4)));

__device__ __forceinline__ float silu(float x){ return x / (1.f + __expf(-x)); }
__device__ __forceinline__ unsigned short f2b(float x){
  unsigned u = __float_as_uint(x);
  unsigned r = u + 0x7FFF + ((u>>16)&1);       // RNE
  return (unsigned short)(r>>16);
}
__device__ __forceinline__ unsigned pkf(float a, float b){
  __hip_bfloat162 h2 = __float22bfloat162_rn(make_float2(a,b));
  return *reinterpret_cast<unsigned*>(&h2);
}

// A-frag LDS swizzle (R8-verified): tile stride 256 dwords; block bi=(row&15)+16*q
// stored at bi ^ (kt&3 + 4*(q&1)); read lane l -> l ^ ((kt&3) + 4*((l>>4)&1)).

// ---------------- one-time weight conversion
__global__ void k_prep(fp gWe1, fp eWc1, fp gWe2, fp eWc2, fp gWn1, fp gWn2,
                       unsigned short* w1b, unsigned short* w2b,
                       unsigned short* wn1b, unsigned short* wn2b){
  int mid = blockIdx.x;
  if (mid < 12){
    const float* src = (mid<8)? gWe1 + (size_t)mid*258*HD : eWc1 + (size_t)(mid-8)*258*HD;
    unsigned short* dst = w1b + (size_t)mid*32768;
    for (int idx = threadIdx.x; idx < 32768; idx += 256){
      int jj = idx&7, l=(idx>>3)&63, kt=(idx>>9)&3, nt=idx>>11;   // nt 0..15
      int k = kt*32 + (l>>4)*8 + jj, n = nt*16 + (l&15);
      dst[idx] = f2b(src[(size_t)(k + ((n>>7)<<7))*HD + (n&127)]);
    }
  } else if (mid < 24){
    int m2 = mid-12;
    const float* src = (m2<8)? gWe2 + (size_t)m2*HD*HD : eWc2 + (size_t)(m2-8)*HD*HD;
    unsigned short* dst = w2b + (size_t)m2*HD*HD;
    for (int idx = threadIdx.x; idx < HD*HD; idx += 256){
      int jj = idx&7, l=(idx>>3)&63, kt=(idx>>9)&3, nt=idx>>11;   // nt 0..7
      int k = kt*32 + (l>>4)*8 + jj, n = nt*16 + (l&15);
      dst[idx] = f2b(src[k*HD+n]);
    }
  } else if (mid < 32){
    int g = mid-24;
    const float* src = gWn1 + (size_t)g*256*HD;
    unsigned short* dst = wn1b + (size_t)g*32768;
    for (int idx = threadIdx.x; idx < 32768; idx += 256){
      int jj = idx&7, l=(idx>>3)&63, kt=(idx>>9)&7, nt=idx>>12;   // kt 0..7, nt 0..7
      int k = kt*32 + (l>>4)*8 + jj, n = nt*16 + (l&15);
      dst[idx] = f2b(src[(size_t)k*HD+n]);
    }
  } else {
    int g = mid-32;
    const float* src = gWn2 + (size_t)g*HD*HD;
    unsigned short* dst = wn2b + (size_t)g*HD*HD;
    for (int idx = threadIdx.x; idx < HD*HD; idx += 256){
      int jj = idx&7, l=(idx>>3)&63, kt=(idx>>9)&3, nt=idx>>11;
      int k = kt*32 + (l>>4)*8 + jj, n = nt*16 + (l&15);
      dst[idx] = f2b(src[k*HD+n]);
    }
  }
}

// ---------------- embedding
__global__ void k_embed(fp xh, fp t, fp nm, fp W_emb, fp b_emb,
                        float* h, float* x0, float* xA){
  int bn = blockIdx.x, tid = threadIdx.x;
  float nmv = nm[bn];
  if (tid < NDIM){
    float v = xh[bn*(NDIM+HFEAT)+tid] * nmv;
    x0[bn*3+tid] = v; xA[bn*3+tid] = v;
  }
  float acc = b_emb[tid];
  #pragma unroll
  for (int f=0; f<HFEAT; ++f)
    acc += xh[bn*(NDIM+HFEAT)+NDIM+f] * nmv * W_emb[f*HD+tid];
  acc += t[0] * W_emb[HFEAT*HD+tid];   // h_time is NOT node-masked
  h[bn*HD+tid] = acc;
}

// ---------------- MFMA hij (standalone, first substep only)
__global__ __launch_bounds__(256) void k_hij(const float* hin, const unsigned short* w1m,
                                             fp b1, float* Hi, float* Hj){
  __shared__ unsigned int hf[4*256];
  int tid=threadIdx.x, blk=blockIdx.x;
  int b = blk/6, mt = blk%6;
  int l=tid&63, w=tid>>6;
  { int kp=l, jsub=w;
    int kt=kp>>4, q=(kp>>2)&3, dsub=kp&3;
    int sm = kt + 4*(q&1);
    float2 hv[4];
    #pragma unroll
    for(int r=0;r<4;++r)
      hv[r] = ((const float2*)&hin[(size_t)(b*Nn+mt*16+jsub*4+r)*HD])[kp];
    #pragma unroll
    for(int r=0;r<4;++r){
      int row=jsub*4+r;
      hf[kt*256 + (((row + 16*q) ^ sm)<<2) + dsub] = pkf(hv[r].x,hv[r].y);
    } }
  __syncthreads();
  f32x4_t acc[4];
  #pragma unroll
  for(int s=0;s<4;++s) acc[s]=(f32x4_t){0.f,0.f,0.f,0.f};
  #pragma unroll
  for(int kt=0;kt<4;++kt){
    int pl = l ^ (kt + 4*((l>>4)&1));
    bf16x8_t A = *(const bf16x8_t*)((const unsigned int*)hf + kt*256 + pl*4);
    #pragma unroll
    for(int s=0;s<4;++s){
      bf16x8_t B = *(const bf16x8_t*)(w1m + ((((w*4+s)*4+kt)*64 + l)*8));
      acc[s]=__builtin_amdgcn_mfma_f32_16x16x32_bf16(A, B, acc[s], 0,0,0);
    }
  }
  #pragma unroll
  for(int s=0;s<4;++s){
    int nt=w*4+s, n=nt*16+(l&15);
    float b1v = (nt<8)? b1[n] : 0.f;
    #pragma unroll
    for(int r=0;r<4;++r){
      int R = b*Nn + mt*16 + (l>>4)*4 + r;
      float v = acc[s][r];
      if(nt<8) Hi[(size_t)R*HD+n] = v + b1v;
      else     Hj[(size_t)R*HD+(n-128)] = v;
    }
  }
}

// ============ fused pair MLP (MFMA), 2 i's per block -> agg ============
// grid = BSZ*48 = 768 (3 blocks/CU resident). LDS ~50 KB.
__global__ __launch_bounds__(256,3) void k_pair(const float* Hi, const float* Hj,
    const float* x, const float* x0, fp nm, fp W1f,
    const unsigned short* w2m, fp b2, float* agg){
  __shared__ unsigned int m1f[2][24*256];  // 48 KB; red[] overlaid after GEMMs
  __shared__ float nms[Nn], rs[2][Nn], d0s[2][Nn];
  int tid=threadIdx.x, blk=blockIdx.x;
  int b=blk/48, i0=(blk%48)*2;
  int l=tid&63, w=tid>>6, wm=w>>1, wn=w&1;
  int jg=w;

  if(tid<Nn) nms[tid]=nm[b*Nn+tid];
  if((tid&127)<Nn){
    int ii=tid>>7, j=tid&127, i=i0+ii;
    const float* xb=&x[(size_t)(b*Nn)*3];
    const float* x0b=&x0[(size_t)(b*Nn)*3];
    float dx0=xb[i*3]-xb[j*3], dx1=xb[i*3+1]-xb[j*3+1], dx2=xb[i*3+2]-xb[j*3+2];
    rs[ii][j]=dx0*dx0+dx1*dx1+dx2*dx2;
    float e0=x0b[i*3]-x0b[j*3], e1=x0b[i*3+1]-x0b[j*3+1], e2=x0b[i*3+2]-x0b[j*3+2];
    d0s[ii][j]=e0*e0+e1*e1+e2*e2;
  }
  __syncthreads();

  // phase 1: m1 for both i's; Hj loaded once per j
  { int kp=l;
    int kt2=kp>>4, qd=(kp>>2)&3, dsub=kp&3;
    int sm=kt2+4*(qd&1);
    float2 hi0=((const float2*)&Hi[(size_t)(b*Nn+i0)*HD])[kp];
    float2 hi1=((const float2*)&Hi[(size_t)(b*Nn+i0+1)*HD])[kp];
    float2 wr=((const float2*)&W1f[(size_t)(2*HD)*HD])[kp];
    float2 wd=((const float2*)&W1f[(size_t)(2*HD+1)*HD])[kp];
    const float2* HjB=(const float2*)&Hj[(size_t)(b*Nn)*HD];
    #pragma unroll
    for(int half=0; half<2; ++half){
      float2 hjv[12];
      #pragma unroll
      for(int u=0;u<12;++u){
        int rr=half*2+(u/6), mt2=u%6;
        int j=mt2*16+jg*4+rr;
        hjv[u]=HjB[(size_t)j*64+kp];
      }
      #pragma unroll
      for(int u=0;u<12;++u){
        int rr=half*2+(u/6), mt2=u%6;
        int jr=jg*4+rr, j=mt2*16+jr;
        unsigned addr = mt2*1024 + kt2*256 + (((jr+16*qd)^sm)<<2) + dsub;
        float r0=rs[0][j], dd0=d0s[0][j];
        float r1=rs[1][j], dd1=d0s[1][j];
        m1f[0][addr]=pkf(silu(hi0.x+hjv[u].x+r0*wr.x+dd0*wd.x),
                         silu(hi0.y+hjv[u].y+r0*wr.y+dd0*wd.y));
        m1f[1][addr]=pkf(silu(hi1.x+hjv[u].x+r1*wr.x+dd1*wd.x),
                         silu(hi1.y+hjv[u].y+r1*wr.y+dd1*wd.y));
      }
    } }
  __syncthreads();

  // GEMM2 + epilogue, sequentially per ii (acc regs reused)
  float b2v[4];
  #pragma unroll
  for(int s=0;s<4;++s) b2v[s]=b2[(wn*4+s)*16 + (l&15)];
  float pv[2][4];
  #pragma unroll
  for(int ii=0; ii<2; ++ii){
    f32x4_t acc[3][4];
    #pragma unroll
    for(int a=0;a<3;++a)
      #pragma unroll
      for(int s=0;s<4;++s) acc[a][s]=(f32x4_t){0.f,0.f,0.f,0.f};
    #pragma unroll
    for(int kt=0;kt<4;++kt){
      int pl = l ^ (kt + 4*((l>>4)&1));
      bf16x8_t Bk[4];
      #pragma unroll
      for(int s=0;s<4;++s)
        Bk[s] = *(const bf16x8_t*)(w2m + ((((wn*4+s)*4+kt)*64 + l)*8));
      #pragma unroll
      for(int a=0;a<3;++a){
        bf16x8_t A = *(const bf16x8_t*)((const unsigned int*)m1f[ii] + (((wm*3+a)*4+kt)*256 + pl*4));
        #pragma unroll
        for(int s=0;s<4;++s)
          acc[a][s]=__builtin_amdgcn_mfma_f32_16x16x32_bf16(A, Bk[s], acc[a][s], 0,0,0);
      }
    }
    float p[4]={0.f,0.f,0.f,0.f};
    int i=i0+ii;
    #pragma unroll
    for(int a=0;a<3;++a)
      #pragma unroll
      for(int r=0;r<4;++r){
        int j=(wm*3+a)*16 + (l>>4)*4 + r;
        float emj=(j==i)?0.f:nms[j];
        #pragma unroll
        for(int s=0;s<4;++s) p[s] += silu(acc[a][s][r]+b2v[s])*emj;
      }
    #pragma unroll
    for(int s=0;s<4;++s){ p[s]+=__shfl_xor(p[s],16); p[s]+=__shfl_xor(p[s],32); pv[ii][s]=p[s]; }
  }
  __syncthreads();           // all m1f reads done -> overlay red
  float* redf=(float*)m1f;   // [wm(2)][ii(2)][128]
  if(l<16){
    #pragma unroll
    for(int ii=0;ii<2;++ii)
      #pragma unroll
      for(int s=0;s<4;++s) redf[(wm*2+ii)*128 + wn*64 + s*16 + l]=pv[ii][s];
  }
  __syncthreads();
  { int ii=tid>>7, c=tid&127;
    agg[(size_t)(b*Nn+i0+ii)*HD+c]=(redf[ii*128+c]+redf[(2+ii)*128+c])*nms[i0+ii]*(1.f/100.f);
  }
}

// ============ MFMA node update + next hij (fused, 16 rows/block, grid 96) ============
__global__ __launch_bounds__(256) void k_nodehij(
    const float* hin, float* hout, const float* agg, fp nm,
    const unsigned short* wn1m, fp bn1v, const unsigned short* wn2m, fp bn2v,
    const unsigned short* w1mA, fp b1A, float* HiA, float* HjA,
    const unsigned short* w1mB, fp b1B, float* HiB, float* HjB){
  __shared__ unsigned int af[8*256];       // A-frags: [h|agg](16x256) -> u -> hout
  __shared__ float fbuf[16*132];           // fp32 staging (stride 132: 2-way banks)
  __shared__ float nmr[16];
  int tid=threadIdx.x, blk=blockIdx.x;
  int b=blk/6, mt=blk%6;
  int R0=b*Nn+mt*16;
  int l=tid&63, w=tid>>6;
  int kp=l, jsub=w;
  int kt0=kp>>4, q=(kp>>2)&3, dsub=kp&3;
  int sm=kt0+4*(q&1);
  if(tid<16) nmr[tid]=nm[R0+tid];
  { float2 hv[4], av[4];
    #pragma unroll
    for(int r=0;r<4;++r){
      hv[r]=((const float2*)&hin[(size_t)(R0+jsub*4+r)*HD])[kp];
      av[r]=((const float2*)&agg[(size_t)(R0+jsub*4+r)*HD])[kp];
    }
    #pragma unroll
    for(int r=0;r<4;++r){
      int row=jsub*4+r;
      unsigned off=(((row+16*q)^sm)<<2)+dsub;
      af[kt0*256+off]=pkf(hv[r].x,hv[r].y);
      af[(4+kt0)*256+off]=pkf(av[r].x,av[r].y);
    } }
  __syncthreads();
  f32x4_t c1[2];
  c1[0]=(f32x4_t){0.f,0.f,0.f,0.f}; c1[1]=(f32x4_t){0.f,0.f,0.f,0.f};
  #pragma unroll
  for(int t=0;t<8;++t){
    int pl = l ^ ((t&3) + 4*((l>>4)&1));
    bf16x8_t A=*(const bf16x8_t*)((const unsigned int*)af + t*256 + pl*4);
    #pragma unroll
    for(int s=0;s<2;++s){
      bf16x8_t B=*(const bf16x8_t*)(wn1m + ((((2*w+s)*8+t)*64+l)*8));
      c1[s]=__builtin_amdgcn_mfma_f32_16x16x32_bf16(A,B,c1[s],0,0,0);
    }
  }
  #pragma unroll
  for(int s=0;s<2;++s){
    int n=(2*w+s)*16+(l&15);
    float bv=bn1v[n];
    #pragma unroll
    for(int r=0;r<4;++r){
      int row=(l>>4)*4+r;
      fbuf[row*132+n]=silu(c1[s][r]+bv);
    }
  }
  __syncthreads();
  #pragma unroll
  for(int r=0;r<4;++r){
    int row=jsub*4+r;
    float2 uv=*(const float2*)&fbuf[row*132+2*kp];
    af[kt0*256 + (((row+16*q)^sm)<<2)+dsub]=pkf(uv.x,uv.y);
  }
  __syncthreads();
  f32x4_t c2[2];
  c2[0]=(f32x4_t){0.f,0.f,0.f,0.f}; c2[1]=(f32x4_t){0.f,0.f,0.f,0.f};
  #pragma unroll
  for(int t=0;t<4;++t){
    int pl = l ^ (t + 4*((l>>4)&1));
    bf16x8_t A=*(const bf16x8_t*)((const unsigned int*)af + t*256 + pl*4);
    #pragma unroll
    for(int s=0;s<2;++s){
      bf16x8_t B=*(const bf16x8_t*)(wn2m + ((((2*w+s)*4+t)*64+l)*8));
      c2[s]=__builtin_amdgcn_mfma_f32_16x16x32_bf16(A,B,c2[s],0,0,0);
    }
  }
  { float hv[2][4];
    #pragma unroll
    for(int s=0;s<2;++s){
      int n=(2*w+s)*16+(l&15);
      #pragma unroll
      for(int r=0;r<4;++r)
        hv[s][r]=hin[(size_t)(R0+(l>>4)*4+r)*HD+n];
    }
    #pragma unroll
    for(int s=0;s<2;++s){
      int n=(2*w+s)*16+(l&15);
      float bv=bn2v[n];
      #pragma unroll
      for(int r=0;r<4;++r){
        int row=(l>>4)*4+r;
        float val=(hv[s][r]+c2[s][r]+bv)*nmr[row];
        hout[(size_t)(R0+row)*HD+n]=val;
        fbuf[row*132+n]=val;
      }
    } }
  __syncthreads();
  #pragma unroll
  for(int r=0;r<4;++r){
    int row=jsub*4+r;
    float2 uv=*(const float2*)&fbuf[row*132+2*kp];
    af[kt0*256 + (((row+16*q)^sm)<<2)+dsub]=pkf(uv.x,uv.y);
  }
  __syncthreads();
  {
    f32x4_t a3[4];
    #pragma unroll
    for(int s=0;s<4;++s) a3[s]=(f32x4_t){0.f,0.f,0.f,0.f};
    #pragma unroll
    for(int t=0;t<4;++t){
      int pl = l ^ (t + 4*((l>>4)&1));
      bf16x8_t A=*(const bf16x8_t*)((const unsigned int*)af + t*256 + pl*4);
      #pragma unroll
      for(int s=0;s<4;++s){
        bf16x8_t B=*(const bf16x8_t*)(w1mA + ((((w*4+s)*4+t)*64+l)*8));
        a3[s]=__builtin_amdgcn_mfma_f32_16x16x32_bf16(A,B,a3[s],0,0,0);
      }
    }
    #pragma unroll
    for(int s=0;s<4;++s){
      int nt=w*4+s, n=nt*16+(l&15);
      float b1v=(nt<8)? b1A[n] : 0.f;
      #pragma unroll
      for(int r=0;r<4;++r){
        int R=R0+(l>>4)*4+r;
        float v=a3[s][r];
        if(nt<8) HiA[(size_t)R*HD+n]=v+b1v;
        else     HjA[(size_t)R*HD+(n-128)]=v;
      }
    }
  }
  if(w1mB){
    f32x4_t a3[4];
    #pragma unroll
    for(int s=0;s<4;++s) a3[s]=(f32x4_t){0.f,0.f,0.f,0.f};
    #pragma unroll
    for(int t=0;t<4;++t){
      int pl = l ^ (t + 4*((l>>4)&1));
      bf16x8_t A=*(const bf16x8_t*)((const unsigned int*)af + t*256 + pl*4);
      #pragma unroll
      for(int s=0;s<4;++s){
        bf16x8_t B=*(const bf16x8_t*)(w1mB + ((((w*4+s)*4+t)*64+l)*8));
        a3[s]=__builtin_amdgcn_mfma_f32_16x16x32_bf16(A,B,a3[s],0,0,0);
      }
    }
    #pragma unroll
    for(int s=0;s<4;++s){
      int nt=w*4+s, n=nt*16+(l&15);
      float b1v=(nt<8)? b1B[n] : 0.f;
      #pragma unroll
      for(int r=0;r<4;++r){
        int R=R0+(l>>4)*4+r;
        float v=a3[s][r];
        if(nt<8) HiB[(size_t)R*HD+n]=v+b1v;
        else     HjB[(size_t)R*HD+(n-128)]=v;
      }
    }
  }
}

// ============ fused coord pair MLP (MFMA), 2 i's per block ============
__global__ __launch_bounds__(256,3) void k_coord(const float* Hi, const float* Hj,
    const float* x, const float* x0, fp nm, fp W1f,
    const unsigned short* w2m, fp b2, fp W3, float* xn){
  __shared__ unsigned int m1f[2][24*256];  // 48 KB; redJ overlaid after GEMMs
  __shared__ float xs[Nn][3], nms[Nn], rs[2][Nn], d0s[2][Nn], sjs[2][Nn];
  int tid=threadIdx.x, blk=blockIdx.x;
  int b=blk/48, i0=(blk%48)*2;
  int l=tid&63, w=tid>>6, wm=w>>1, wn=w&1;
  int jg=w;

  for(int idx=tid; idx<Nn*3; idx+=256){ int n=idx/3,d=idx%3;
    xs[n][d]=x[(b*Nn+n)*3+d]; }
  if(tid<Nn) nms[tid]=nm[b*Nn+tid];
  if((tid&127)<Nn){
    int ii=tid>>7, j=tid&127, i=i0+ii;
    const float* xb=&x[(size_t)(b*Nn)*3];
    const float* x0b=&x0[(size_t)(b*Nn)*3];
    float dx0=xb[i*3]-xb[j*3], dx1=xb[i*3+1]-xb[j*3+1], dx2=xb[i*3+2]-xb[j*3+2];
    rs[ii][j]=dx0*dx0+dx1*dx1+dx2*dx2;
    float e0=x0b[i*3]-x0b[j*3], e1=x0b[i*3+1]-x0b[j*3+1], e2=x0b[i*3+2]-x0b[j*3+2];
    d0s[ii][j]=e0*e0+e1*e1+e2*e2;
  }
  __syncthreads();

  { int kp=l;
    int kt2=kp>>4, qd=(kp>>2)&3, dsub=kp&3;
    int sm=kt2+4*(qd&1);
    float2 hi0=((const float2*)&Hi[(size_t)(b*Nn+i0)*HD])[kp];
    float2 hi1=((const float2*)&Hi[(size_t)(b*Nn+i0+1)*HD])[kp];
    float2 wr=((const float2*)&W1f[(size_t)(2*HD)*HD])[kp];
    float2 wd=((const float2*)&W1f[(size_t)(2*HD+1)*HD])[kp];
    const float2* HjB=(const float2*)&Hj[(size_t)(b*Nn)*HD];
    #pragma unroll
    for(int half=0; half<2; ++half){
      float2 hjv[12];
      #pragma unroll
      for(int u=0;u<12;++u){
        int rr=half*2+(u/6), mt2=u%6;
        int j=mt2*16+jg*4+rr;
        hjv[u]=HjB[(size_t)j*64+kp];
      }
      #pragma unroll
      for(int u=0;u<12;++u){
        int rr=half*2+(u/6), mt2=u%6;
        int jr=jg*4+rr, j=mt2*16+jr;
        unsigned addr = mt2*1024 + kt2*256 + (((jr+16*qd)^sm)<<2) + dsub;
        float r0=rs[0][j], dd0=d0s[0][j];
        float r1=rs[1][j], dd1=d0s[1][j];
        m1f[0][addr]=pkf(silu(hi0.x+hjv[u].x+r0*wr.x+dd0*wd.x),
                         silu(hi0.y+hjv[u].y+r0*wr.y+dd0*wd.y));
        m1f[1][addr]=pkf(silu(hi1.x+hjv[u].x+r1*wr.x+dd1*wd.x),
                         silu(hi1.y+hjv[u].y+r1*wr.y+dd1*wd.y));
      }
    } }
  __syncthreads();

  float b2v[4], w3v[4];
  #pragma unroll
  for(int s=0;s<4;++s){ b2v[s]=b2[(wn*4+s)*16+(l&15)]; w3v[s]=W3[(wn*4+s)*16+(l&15)]; }
  float qvv[2][3][4];
  #pragma unroll
  for(int ii=0; ii<2; ++ii){
    f32x4_t acc[3][4];
    #pragma unroll
    for(int a=0;a<3;++a)
      #pragma unroll
      for(int s=0;s<4;++s) acc[a][s]=(f32x4_t){0.f,0.f,0.f,0.f};
    #pragma unroll
    for(int kt=0;kt<4;++kt){
      int pl = l ^ (kt + 4*((l>>4)&1));
      bf16x8_t Bk[4];
      #pragma unroll
      for(int s=0;s<4;++s)
        Bk[s] = *(const bf16x8_t*)(w2m + ((((wn*4+s)*4+kt)*64 + l)*8));
      #pragma unroll
      for(int a=0;a<3;++a){
        bf16x8_t A = *(const bf16x8_t*)((const unsigned int*)m1f[ii] + (((wm*3+a)*4+kt)*256 + pl*4));
        #pragma unroll
        for(int s=0;s<4;++s)
          acc[a][s]=__builtin_amdgcn_mfma_f32_16x16x32_bf16(A, Bk[s], acc[a][s], 0,0,0);
      }
    }
    #pragma unroll
    for(int a=0;a<3;++a)
      #pragma unroll
      for(int r=0;r<4;++r){
        float pj=0.f;
        #pragma unroll
        for(int s=0;s<4;++s) pj += silu(acc[a][s][r]+b2v[s])*w3v[s];
        qvv[ii][a][r]=pj;
      }
    #pragma unroll
    for(int d=1;d<16;d<<=1)
      #pragma unroll
      for(int a=0;a<3;++a)
        #pragma unroll
        for(int r=0;r<4;++r)
          qvv[ii][a][r] += __shfl_xor(qvv[ii][a][r], d);
  }
  __syncthreads();           // all m1f reads done -> overlay redJ
  float* redjf=(float*)m1f;  // [wn(2)][ii(2)][96]
  if((l&15)==0){
    int quad=l>>4;
    #pragma unroll
    for(int ii=0;ii<2;++ii)
      #pragma unroll
      for(int a=0;a<3;++a)
        #pragma unroll
        for(int r=0;r<4;++r)
          redjf[(wn*2+ii)*Nn + (wm*3+a)*16 + quad*4 + r]=qvv[ii][a][r];
  }
  __syncthreads();
  if((tid&127)<Nn){
    int ii=tid>>7, j=tid&127, i=i0+ii;
    float pj=redjf[ii*Nn+j]+redjf[(2+ii)*Nn+j];
    float em=(j==i)?0.f:nms[j];
    sjs[ii][j]=pj*em*rsqrtf(rs[ii][j]+1e-8f);
  }
  __syncthreads();
  if(w<3){
    int d=w;
    #pragma unroll
    for(int ii=0;ii<2;++ii){
      int i=i0+ii;
      float xi=xs[i][d];
      float s=(xi-xs[l][d])*sjs[ii][l];
      if(l<32) s += (xi-xs[l+64][d])*sjs[ii][l+64];
      s+=__shfl_xor(s,1); s+=__shfl_xor(s,2); s+=__shfl_xor(s,4);
      s+=__shfl_xor(s,8); s+=__shfl_xor(s,16); s+=__shfl_xor(s,32);
      if(l==0) xn[(size_t)(b*Nn+i)*3+d]=(xi+s*(1.f/100.f))*nms[i];
    }
  }
}

// ---------------- per-batch vel stats
__global__ void k_velstat(const float* xf, const float* x0, fp nm, float* vstat){
  __shared__ float sh[128];
  int b=blockIdx.x, tid=threadIdx.x;
  float nmv = (tid<Nn)? nm[b*Nn+tid] : 0.f;
  float vals[4];
  #pragma unroll
  for(int d=0;d<3;++d)
    vals[d] = (tid<Nn)? (xf[(b*Nn+tid)*3+d]-x0[(b*Nn+tid)*3+d])*nmv : 0.f;
  vals[3]=nmv;
  #pragma unroll
  for(int q=0;q<4;++q){
    sh[tid]=vals[q]; __syncthreads();
    for(int s=64;s>0;s>>=1){ if(tid<s) sh[tid]+=sh[tid+s]; __syncthreads(); }
    if(tid==0) vstat[b*4+q]=sh[0];
    __syncthreads();
  }
}

// ---------------- output
__global__ void k_out(const float* h, const float* xf, const float* x0, fp nm,
                      const float* vstat, fp W_out, fp b_out, float* out){
  __shared__ float shh[HD];
  int bn=blockIdx.x, tid=threadIdx.x, b=bn/Nn;
  shh[tid]=h[bn*HD+tid]; __syncthreads();
  float nmv=nm[bn];
  if(tid<3){
    float vel=(xf[bn*3+tid]-x0[bn*3+tid])*nmv;
    float mean=vstat[b*4+tid]/vstat[b*4+3];
    out[bn*(NDIM+HFEAT)+tid]=vel-mean*nmv;
  } else if(tid<3+HFEAT){
    int f=tid-3;
    float acc=b_out[f];
    for(int k=0;k<HD;++k) acc+=shh[k]*W_out[k*FINC+f];
    out[bn*(NDIM+HFEAT)+tid]=acc*nmv;
  }
}

extern "C" void kernel_launch(void* const* d_in, const int* in_sizes, int n_in,
                              void* d_out, int out_size, void* d_ws, size_t ws_size,
                              hipStream_t stream) {
  fp xh   =(fp)d_in[0];
  fp t    =(fp)d_in[1];
  fp nm   =(fp)d_in[2];
  // d_in[3] edge_mask: reproduced exactly as nm_i*nm_j*(i!=j), not read
  fp W_emb=(fp)d_in[4],  b_emb=(fp)d_in[5];
  fp gWe1 =(fp)d_in[6],  gbe1 =(fp)d_in[7];
  fp gWe2 =(fp)d_in[8],  gbe2 =(fp)d_in[9];
  fp gWn1 =(fp)d_in[10], gbn1 =(fp)d_in[11];
  fp gWn2 =(fp)d_in[12], gbn2 =(fp)d_in[13];
  fp eWc1 =(fp)d_in[14], ebc1 =(fp)d_in[15];
  fp eWc2 =(fp)d_in[16], ebc2 =(fp)d_in[17];
  fp eWc3 =(fp)d_in[18];
  fp W_out=(fp)d_in[19], b_out=(fp)d_in[20];

  unsigned short* w1b  = (unsigned short*)d_ws;            // 12*32768
  unsigned short* w2b  = w1b  + (size_t)12*32768;          // 12*16384
  unsigned short* wn1b = w2b  + (size_t)12*16384;          // 8*32768
  unsigned short* wn2b = wn1b + (size_t)8*32768;           // 8*16384
  float* fbase = (float*)(wn2b + (size_t)8*16384);
  float* hA   = fbase;            // BN*HD each
  float* hB   = hA  + BN*HD;
  float* HiA  = hB  + BN*HD;
  float* HjA  = HiA + BN*HD;
  float* HiE  = HjA + BN*HD;
  float* HjE  = HiE + BN*HD;
  float* agg  = HjE + BN*HD;
  float* x0   = agg + BN*HD;      // BN*3
  float* xA   = x0  + BN*3;
  float* xB   = xA  + BN*3;
  float* vstat= xB  + BN*3;       // BSZ*4

  k_prep <<<40,256,0,stream>>>(gWe1, eWc1, gWe2, eWc2, gWn1, gWn2, w1b, w2b, wn1b, wn2b);
  k_embed<<<BN,128,0,stream>>>(xh,t,nm,W_emb,b_emb,hA,x0,xA);
  k_hij  <<<96,256,0,stream>>>(hA, w1b, gbe1, HiA, HjA);
  float *hc=hA, *hn=hB, *xc=xA, *xn=xB;
  for(int l=0;l<4;++l){
    int g=2*l;
    k_pair<<<BN/2,256,0,stream>>>(HiA,HjA,xc,x0,nm, gWe1+(size_t)g*258*HD,
          w2b+(size_t)g*HD*HD, gbe2+(size_t)g*HD, agg);
    k_nodehij<<<96,256,0,stream>>>(hc,hn,agg,nm,
          wn1b+(size_t)g*32768, gbn1+(size_t)g*HD,
          wn2b+(size_t)g*16384, gbn2+(size_t)g*HD,
          w1b+(size_t)(g+1)*32768, gbe1+(size_t)(g+1)*HD, HiA, HjA,
          nullptr, nullptr, nullptr, nullptr);
    { float* tmp=hc; hc=hn; hn=tmp; }
    g=2*l+1;
    k_pair<<<BN/2,256,0,stream>>>(HiA,HjA,xc,x0,nm, gWe1+(size_t)g*258*HD,
          w2b+(size_t)g*HD*HD, gbe2+(size_t)g*HD, agg);
    bool last = (l==3);
    k_nodehij<<<96,256,0,stream>>>(hc,hn,agg,nm,
          wn1b+(size_t)g*32768, gbn1+(size_t)g*HD,
          wn2b+(size_t)g*16384, gbn2+(size_t)g*HD,
          w1b+(size_t)(8+l)*32768, ebc1+(size_t)l*HD, HiE, HjE,
          last? nullptr : w1b+(size_t)(g+1)*32768,
          last? nullptr : gbe1+(size_t)(g+1)*HD, HiA, HjA);
    { float* tmp=hc; hc=hn; hn=tmp; }
    k_coord<<<BN/2,256,0,stream>>>(HiE,HjE,xc,x0,nm, eWc1+(size_t)l*258*HD,
          w2b+(size_t)(8+l)*HD*HD, ebc2+(size_t)l*HD,
          eWc3+(size_t)l*HD, xn);
    { float* tmp=xc; xc=xn; xn=tmp; }
  }
  k_velstat<<<BSZ,128,0,stream>>>(xc,x0,nm,vstat);
  k_out   <<<BN,128,0,stream>>>(hc,xc,x0,nm,vstat,W_out,b_out,(float*)d_out);
}

// Round 12
// 429.006 us; speedup vs baseline: 1.2471x; 1.2471x over previous
//
#include <hip/hip_runtime.h>
#include <hip/hip_bf16.h>

#define BSZ 16
#define Nn 96
#define HD 128
#define NDIM 3
#define HFEAT 6
#define FINC 7
#define BN (BSZ*Nn)

typedef const float* fp;
typedef __bf16 bf16x8_t __attribute__((ext_vector_type(8)));
typedef float  f32x4_t  __attribute__((ext_vector_type(4)));

// silu via v_exp + v_rcp (approx, ~1 ulp) — avoids the fp32 div_scale/fmas/fixup
// sequence (~12 VALU insts -> 4). This is the dominant VALU cost of the whole net.
__device__ __forceinline__ float silu(float x){
  float e = __expf(-x);
  return x * __builtin_amdgcn_rcpf(1.f + e);
}
__device__ __forceinline__ unsigned short f2b(float x){
  unsigned u = __float_as_uint(x);
  unsigned r = u + 0x7FFF + ((u>>16)&1);       // RNE
  return (unsigned short)(r>>16);
}
__device__ __forceinline__ unsigned pkf(float a, float b){
  __hip_bfloat162 h2 = __float22bfloat162_rn(make_float2(a,b));
  return *reinterpret_cast<unsigned*>(&h2);
}

// A-frag LDS swizzle (R8-verified): tile stride 256 dwords; block bi=(row&15)+16*q
// stored at bi ^ (kt&3 + 4*(q&1)); read lane l -> l ^ ((kt&3) + 4*((l>>4)&1)).

// ---------------- one-time weight conversion
__global__ void k_prep(fp gWe1, fp eWc1, fp gWe2, fp eWc2, fp gWn1, fp gWn2,
                       unsigned short* w1b, unsigned short* w2b,
                       unsigned short* wn1b, unsigned short* wn2b){
  int mid = blockIdx.x;
  if (mid < 12){
    const float* src = (mid<8)? gWe1 + (size_t)mid*258*HD : eWc1 + (size_t)(mid-8)*258*HD;
    unsigned short* dst = w1b + (size_t)mid*32768;
    for (int idx = threadIdx.x; idx < 32768; idx += 256){
      int jj = idx&7, l=(idx>>3)&63, kt=(idx>>9)&3, nt=idx>>11;   // nt 0..15
      int k = kt*32 + (l>>4)*8 + jj, n = nt*16 + (l&15);
      dst[idx] = f2b(src[(size_t)(k + ((n>>7)<<7))*HD + (n&127)]);
    }
  } else if (mid < 24){
    int m2 = mid-12;
    const float* src = (m2<8)? gWe2 + (size_t)m2*HD*HD : eWc2 + (size_t)(m2-8)*HD*HD;
    unsigned short* dst = w2b + (size_t)m2*HD*HD;
    for (int idx = threadIdx.x; idx < HD*HD; idx += 256){
      int jj = idx&7, l=(idx>>3)&63, kt=(idx>>9)&3, nt=idx>>11;   // nt 0..7
      int k = kt*32 + (l>>4)*8 + jj, n = nt*16 + (l&15);
      dst[idx] = f2b(src[k*HD+n]);
    }
  } else if (mid < 32){
    int g = mid-24;
    const float* src = gWn1 + (size_t)g*256*HD;
    unsigned short* dst = wn1b + (size_t)g*32768;
    for (int idx = threadIdx.x; idx < 32768; idx += 256){
      int jj = idx&7, l=(idx>>3)&63, kt=(idx>>9)&7, nt=idx>>12;   // kt 0..7, nt 0..7
      int k = kt*32 + (l>>4)*8 + jj, n = nt*16 + (l&15);
      dst[idx] = f2b(src[(size_t)k*HD+n]);
    }
  } else {
    int g = mid-32;
    const float* src = gWn2 + (size_t)g*HD*HD;
    unsigned short* dst = wn2b + (size_t)g*HD*HD;
    for (int idx = threadIdx.x; idx < HD*HD; idx += 256){
      int jj = idx&7, l=(idx>>3)&63, kt=(idx>>9)&3, nt=idx>>11;
      int k = kt*32 + (l>>4)*8 + jj, n = nt*16 + (l&15);
      dst[idx] = f2b(src[k*HD+n]);
    }
  }
}

// ---------------- embedding
__global__ void k_embed(fp xh, fp t, fp nm, fp W_emb, fp b_emb,
                        float* h, float* x0, float* xA){
  int bn = blockIdx.x, tid = threadIdx.x;
  float nmv = nm[bn];
  if (tid < NDIM){
    float v = xh[bn*(NDIM+HFEAT)+tid] * nmv;
    x0[bn*3+tid] = v; xA[bn*3+tid] = v;
  }
  float acc = b_emb[tid];
  #pragma unroll
  for (int f=0; f<HFEAT; ++f)
    acc += xh[bn*(NDIM+HFEAT)+NDIM+f] * nmv * W_emb[f*HD+tid];
  acc += t[0] * W_emb[HFEAT*HD+tid];   // h_time is NOT node-masked
  h[bn*HD+tid] = acc;
}

// ---------------- MFMA hij (standalone, first substep only)
__global__ __launch_bounds__(256) void k_hij(const float* hin, const unsigned short* w1m,
                                             fp b1, float* Hi, float* Hj){
  __shared__ unsigned int hf[4*256];
  int tid=threadIdx.x, blk=blockIdx.x;
  int b = blk/6, mt = blk%6;
  int l=tid&63, w=tid>>6;
  { int kp=l, jsub=w;
    int kt=kp>>4, q=(kp>>2)&3, dsub=kp&3;
    int sm = kt + 4*(q&1);
    float2 hv[4];
    #pragma unroll
    for(int r=0;r<4;++r)
      hv[r] = ((const float2*)&hin[(size_t)(b*Nn+mt*16+jsub*4+r)*HD])[kp];
    #pragma unroll
    for(int r=0;r<4;++r){
      int row=jsub*4+r;
      hf[kt*256 + (((row + 16*q) ^ sm)<<2) + dsub] = pkf(hv[r].x,hv[r].y);
    } }
  __syncthreads();
  f32x4_t acc[4];
  #pragma unroll
  for(int s=0;s<4;++s) acc[s]=(f32x4_t){0.f,0.f,0.f,0.f};
  #pragma unroll
  for(int kt=0;kt<4;++kt){
    int pl = l ^ (kt + 4*((l>>4)&1));
    bf16x8_t A = *(const bf16x8_t*)((const unsigned int*)hf + kt*256 + pl*4);
    #pragma unroll
    for(int s=0;s<4;++s){
      bf16x8_t B = *(const bf16x8_t*)(w1m + ((((w*4+s)*4+kt)*64 + l)*8));
      acc[s]=__builtin_amdgcn_mfma_f32_16x16x32_bf16(A, B, acc[s], 0,0,0);
    }
  }
  #pragma unroll
  for(int s=0;s<4;++s){
    int nt=w*4+s, n=nt*16+(l&15);
    float b1v = (nt<8)? b1[n] : 0.f;
    #pragma unroll
    for(int r=0;r<4;++r){
      int R = b*Nn + mt*16 + (l>>4)*4 + r;
      float v = acc[s][r];
      if(nt<8) Hi[(size_t)R*HD+n] = v + b1v;
      else     Hj[(size_t)R*HD+(n-128)] = v;
    }
  }
}

// ============ fused pair MLP (MFMA) + aggregate -> agg ============
__global__ __launch_bounds__(256,4) void k_pair(const float* Hi, const float* Hj,
    const float* x, const float* x0, fp nm, fp W1f,
    const unsigned short* w2m, fp b2, float* agg){
  __shared__ unsigned int m1f[24*256];     // 24 KB swizzled A-frags
  __shared__ float xs[Nn][3], x0s[Nn][3], nms[Nn], rs[Nn], d0s[Nn];
  __shared__ float red[2][HD];
  int tid=threadIdx.x, bn=blockIdx.x;
  int b=bn/Nn, i=bn%Nn;
  int l=tid&63, w=tid>>6, wm=w>>1, wn=w&1;
  int jg=w;

  for(int idx=tid; idx<Nn*3; idx+=256){ int n=idx/3,d=idx%3;
    xs[n][d]=x[(b*Nn+n)*3+d]; x0s[n][d]=x0[(b*Nn+n)*3+d]; }
  if(tid<Nn) nms[tid]=nm[b*Nn+tid];
  __syncthreads();
  if(tid<Nn){
    float dx0=xs[i][0]-xs[tid][0], dx1=xs[i][1]-xs[tid][1], dx2=xs[i][2]-xs[tid][2];
    rs[tid]=dx0*dx0+dx1*dx1+dx2*dx2;
    float e0=x0s[i][0]-x0s[tid][0], e1=x0s[i][1]-x0s[tid][1], e2=x0s[i][2]-x0s[tid][2];
    d0s[tid]=e0*e0+e1*e1+e2*e2;
  }
  __syncthreads();

  // phase 1: m1[j][k] = silu(Hi+Hj+r*wr+d0*wd); Hj loads batched 12-deep
  { int kp=l;
    int kt2=kp>>4, q=(kp>>2)&3, dsub=kp&3;
    int sm=kt2+4*(q&1);
    float2 hi=((const float2*)&Hi[(size_t)bn*HD])[kp];
    float2 wr=((const float2*)&W1f[(size_t)(2*HD)*HD])[kp];
    float2 wd=((const float2*)&W1f[(size_t)(2*HD+1)*HD])[kp];
    const float2* HjB=(const float2*)&Hj[(size_t)(b*Nn)*HD];
    #pragma unroll
    for(int half=0; half<2; ++half){
      float2 hjv[12];
      #pragma unroll
      for(int u=0;u<12;++u){
        int rr=half*2+(u/6), mt2=u%6;
        int j=mt2*16+jg*4+rr;
        hjv[u]=HjB[(size_t)j*64+kp];
      }
      #pragma unroll
      for(int u=0;u<12;++u){
        int rr=half*2+(u/6), mt2=u%6;
        int jr=jg*4+rr, j=mt2*16+jr;
        float rv=rs[j], dv=d0s[j];
        float m0 =silu(hi.x+hjv[u].x+rv*wr.x+dv*wd.x);
        float m1v=silu(hi.y+hjv[u].y+rv*wr.y+dv*wd.y);
        m1f[mt2*1024 + kt2*256 + (((jr+16*q)^sm)<<2) + dsub]=pkf(m0,m1v);
      }
    } }
  __syncthreads();

  // GEMM2: wave (wm,wn): mt=wm*3..+2, nt=wn*4..+3
  f32x4_t acc[3][4];
  #pragma unroll
  for(int a=0;a<3;++a)
    #pragma unroll
    for(int s=0;s<4;++s) acc[a][s]=(f32x4_t){0.f,0.f,0.f,0.f};
  #pragma unroll
  for(int kt=0;kt<4;++kt){
    int pl = l ^ (kt + 4*((l>>4)&1));
    bf16x8_t Bk[4];
    #pragma unroll
    for(int s=0;s<4;++s)
      Bk[s] = *(const bf16x8_t*)(w2m + ((((wn*4+s)*4+kt)*64 + l)*8));
    #pragma unroll
    for(int a=0;a<3;++a){
      bf16x8_t A = *(const bf16x8_t*)((const unsigned int*)m1f + (((wm*3+a)*4+kt)*256 + pl*4));
      #pragma unroll
      for(int s=0;s<4;++s)
        acc[a][s]=__builtin_amdgcn_mfma_f32_16x16x32_bf16(A, Bk[s], acc[a][s], 0,0,0);
    }
  }

  // epilogue: silu(+b2)*em, reduce over j -> agg
  float b2v[4], p[4]={0.f,0.f,0.f,0.f};
  #pragma unroll
  for(int s=0;s<4;++s) b2v[s]=b2[(wn*4+s)*16 + (l&15)];
  #pragma unroll
  for(int a=0;a<3;++a)
    #pragma unroll
    for(int r=0;r<4;++r){
      int j=(wm*3+a)*16 + (l>>4)*4 + r;
      float emj=(j==i)?0.f:nms[j];
      #pragma unroll
      for(int s=0;s<4;++s) p[s] += silu(acc[a][s][r]+b2v[s])*emj;
    }
  #pragma unroll
  for(int s=0;s<4;++s){ p[s]+=__shfl_xor(p[s],16); p[s]+=__shfl_xor(p[s],32); }
  if(l<16){
    #pragma unroll
    for(int s=0;s<4;++s) red[wm][wn*64 + s*16 + l]=p[s];
  }
  __syncthreads();
  if(tid<HD) agg[(size_t)bn*HD+tid]=(red[0][tid]+red[1][tid])*nms[i]*(1.f/100.f);
}

// ============ MFMA node update + next hij (fused, 16 rows/block, grid 96) ============
__global__ __launch_bounds__(256) void k_nodehij(
    const float* hin, float* hout, const float* agg, fp nm,
    const unsigned short* wn1m, fp bn1v, const unsigned short* wn2m, fp bn2v,
    const unsigned short* w1mA, fp b1A, float* HiA, float* HjA,
    const unsigned short* w1mB, fp b1B, float* HiB, float* HjB){
  __shared__ unsigned int af[8*256];       // A-frags: [h|agg](16x256) -> u -> hout
  __shared__ float fbuf[16*132];           // fp32 staging (stride 132: 2-way banks)
  __shared__ float nmr[16];
  int tid=threadIdx.x, blk=blockIdx.x;
  int b=blk/6, mt=blk%6;
  int R0=b*Nn+mt*16;
  int l=tid&63, w=tid>>6;
  int kp=l, jsub=w;
  int kt0=kp>>4, q=(kp>>2)&3, dsub=kp&3;
  int sm=kt0+4*(q&1);
  if(tid<16) nmr[tid]=nm[R0+tid];
  { float2 hv[4], av[4];
    #pragma unroll
    for(int r=0;r<4;++r){
      hv[r]=((const float2*)&hin[(size_t)(R0+jsub*4+r)*HD])[kp];
      av[r]=((const float2*)&agg[(size_t)(R0+jsub*4+r)*HD])[kp];
    }
    #pragma unroll
    for(int r=0;r<4;++r){
      int row=jsub*4+r;
      unsigned off=(((row+16*q)^sm)<<2)+dsub;
      af[kt0*256+off]=pkf(hv[r].x,hv[r].y);
      af[(4+kt0)*256+off]=pkf(av[r].x,av[r].y);
    } }
  __syncthreads();
  f32x4_t c1[2];
  c1[0]=(f32x4_t){0.f,0.f,0.f,0.f}; c1[1]=(f32x4_t){0.f,0.f,0.f,0.f};
  #pragma unroll
  for(int t=0;t<8;++t){
    int pl = l ^ ((t&3) + 4*((l>>4)&1));
    bf16x8_t A=*(const bf16x8_t*)((const unsigned int*)af + t*256 + pl*4);
    #pragma unroll
    for(int s=0;s<2;++s){
      bf16x8_t B=*(const bf16x8_t*)(wn1m + ((((2*w+s)*8+t)*64+l)*8));
      c1[s]=__builtin_amdgcn_mfma_f32_16x16x32_bf16(A,B,c1[s],0,0,0);
    }
  }
  #pragma unroll
  for(int s=0;s<2;++s){
    int n=(2*w+s)*16+(l&15);
    float bv=bn1v[n];
    #pragma unroll
    for(int r=0;r<4;++r){
      int row=(l>>4)*4+r;
      fbuf[row*132+n]=silu(c1[s][r]+bv);
    }
  }
  __syncthreads();
  #pragma unroll
  for(int r=0;r<4;++r){
    int row=jsub*4+r;
    float2 uv=*(const float2*)&fbuf[row*132+2*kp];
    af[kt0*256 + (((row+16*q)^sm)<<2)+dsub]=pkf(uv.x,uv.y);
  }
  __syncthreads();
  f32x4_t c2[2];
  c2[0]=(f32x4_t){0.f,0.f,0.f,0.f}; c2[1]=(f32x4_t){0.f,0.f,0.f,0.f};
  #pragma unroll
  for(int t=0;t<4;++t){
    int pl = l ^ (t + 4*((l>>4)&1));
    bf16x8_t A=*(const bf16x8_t*)((const unsigned int*)af + t*256 + pl*4);
    #pragma unroll
    for(int s=0;s<2;++s){
      bf16x8_t B=*(const bf16x8_t*)(wn2m + ((((2*w+s)*4+t)*64+l)*8));
      c2[s]=__builtin_amdgcn_mfma_f32_16x16x32_bf16(A,B,c2[s],0,0,0);
    }
  }
  { float hv[2][4];
    #pragma unroll
    for(int s=0;s<2;++s){
      int n=(2*w+s)*16+(l&15);
      #pragma unroll
      for(int r=0;r<4;++r)
        hv[s][r]=hin[(size_t)(R0+(l>>4)*4+r)*HD+n];
    }
    #pragma unroll
    for(int s=0;s<2;++s){
      int n=(2*w+s)*16+(l&15);
      float bv=bn2v[n];
      #pragma unroll
      for(int r=0;r<4;++r){
        int row=(l>>4)*4+r;
        float val=(hv[s][r]+c2[s][r]+bv)*nmr[row];
        hout[(size_t)(R0+row)*HD+n]=val;
        fbuf[row*132+n]=val;
      }
    } }
  __syncthreads();
  #pragma unroll
  for(int r=0;r<4;++r){
    int row=jsub*4+r;
    float2 uv=*(const float2*)&fbuf[row*132+2*kp];
    af[kt0*256 + (((row+16*q)^sm)<<2)+dsub]=pkf(uv.x,uv.y);
  }
  __syncthreads();
  {
    f32x4_t a3[4];
    #pragma unroll
    for(int s=0;s<4;++s) a3[s]=(f32x4_t){0.f,0.f,0.f,0.f};
    #pragma unroll
    for(int t=0;t<4;++t){
      int pl = l ^ (t + 4*((l>>4)&1));
      bf16x8_t A=*(const bf16x8_t*)((const unsigned int*)af + t*256 + pl*4);
      #pragma unroll
      for(int s=0;s<4;++s){
        bf16x8_t B=*(const bf16x8_t*)(w1mA + ((((w*4+s)*4+t)*64+l)*8));
        a3[s]=__builtin_amdgcn_mfma_f32_16x16x32_bf16(A,B,a3[s],0,0,0);
      }
    }
    #pragma unroll
    for(int s=0;s<4;++s){
      int nt=w*4+s, n=nt*16+(l&15);
      float b1v=(nt<8)? b1A[n] : 0.f;
      #pragma unroll
      for(int r=0;r<4;++r){
        int R=R0+(l>>4)*4+r;
        float v=a3[s][r];
        if(nt<8) HiA[(size_t)R*HD+n]=v+b1v;
        else     HjA[(size_t)R*HD+(n-128)]=v;
      }
    }
  }
  if(w1mB){
    f32x4_t a3[4];
    #pragma unroll
    for(int s=0;s<4;++s) a3[s]=(f32x4_t){0.f,0.f,0.f,0.f};
    #pragma unroll
    for(int t=0;t<4;++t){
      int pl = l ^ (t + 4*((l>>4)&1));
      bf16x8_t A=*(const bf16x8_t*)((const unsigned int*)af + t*256 + pl*4);
      #pragma unroll
      for(int s=0;s<4;++s){
        bf16x8_t B=*(const bf16x8_t*)(w1mB + ((((w*4+s)*4+t)*64+l)*8));
        a3[s]=__builtin_amdgcn_mfma_f32_16x16x32_bf16(A,B,a3[s],0,0,0);
      }
    }
    #pragma unroll
    for(int s=0;s<4;++s){
      int nt=w*4+s, n=nt*16+(l&15);
      float b1v=(nt<8)? b1B[n] : 0.f;
      #pragma unroll
      for(int r=0;r<4;++r){
        int R=R0+(l>>4)*4+r;
        float v=a3[s][r];
        if(nt<8) HiB[(size_t)R*HD+n]=v+b1v;
        else     HjB[(size_t)R*HD+(n-128)]=v;
      }
    }
  }
}

// ============ fused coord pair MLP (MFMA) ============
__global__ __launch_bounds__(256,4) void k_coord(const float* Hi, const float* Hj,
    const float* x, const float* x0, fp nm, fp W1f,
    const unsigned short* w2m, fp b2, fp W3, float* xn){
  __shared__ unsigned int m1f[24*256];
  __shared__ float xs[Nn][3], x0s[Nn][3], nms[Nn], rs[Nn], d0s[Nn];
  __shared__ float redJ[2][Nn];
  __shared__ float sjs[Nn];
  int tid=threadIdx.x, bn=blockIdx.x;
  int b=bn/Nn, i=bn%Nn;
  int l=tid&63, w=tid>>6, wm=w>>1, wn=w&1;
  int jg=w;

  for(int idx=tid; idx<Nn*3; idx+=256){ int n=idx/3,d=idx%3;
    xs[n][d]=x[(b*Nn+n)*3+d]; x0s[n][d]=x0[(b*Nn+n)*3+d]; }
  if(tid<Nn) nms[tid]=nm[b*Nn+tid];
  __syncthreads();
  if(tid<Nn){
    float dx0=xs[i][0]-xs[tid][0], dx1=xs[i][1]-xs[tid][1], dx2=xs[i][2]-xs[tid][2];
    rs[tid]=dx0*dx0+dx1*dx1+dx2*dx2;
    float e0=x0s[i][0]-x0s[tid][0], e1=x0s[i][1]-x0s[tid][1], e2=x0s[i][2]-x0s[tid][2];
    d0s[tid]=e0*e0+e1*e1+e2*e2;
  }
  __syncthreads();

  { int kp=l;
    int kt2=kp>>4, q=(kp>>2)&3, dsub=kp&3;
    int sm=kt2+4*(q&1);
    float2 hi=((const float2*)&Hi[(size_t)bn*HD])[kp];
    float2 wr=((const float2*)&W1f[(size_t)(2*HD)*HD])[kp];
    float2 wd=((const float2*)&W1f[(size_t)(2*HD+1)*HD])[kp];
    const float2* HjB=(const float2*)&Hj[(size_t)(b*Nn)*HD];
    #pragma unroll
    for(int half=0; half<2; ++half){
      float2 hjv[12];
      #pragma unroll
      for(int u=0;u<12;++u){
        int rr=half*2+(u/6), mt2=u%6;
        int j=mt2*16+jg*4+rr;
        hjv[u]=HjB[(size_t)j*64+kp];
      }
      #pragma unroll
      for(int u=0;u<12;++u){
        int rr=half*2+(u/6), mt2=u%6;
        int jr=jg*4+rr, j=mt2*16+jr;
        float rv=rs[j], dv=d0s[j];
        float m0 =silu(hi.x+hjv[u].x+rv*wr.x+dv*wd.x);
        float m1v=silu(hi.y+hjv[u].y+rv*wr.y+dv*wd.y);
        m1f[mt2*1024 + kt2*256 + (((jr+16*q)^sm)<<2) + dsub]=pkf(m0,m1v);
      }
    } }
  __syncthreads();

  f32x4_t acc[3][4];
  #pragma unroll
  for(int a=0;a<3;++a)
    #pragma unroll
    for(int s=0;s<4;++s) acc[a][s]=(f32x4_t){0.f,0.f,0.f,0.f};
  #pragma unroll
  for(int kt=0;kt<4;++kt){
    int pl = l ^ (kt + 4*((l>>4)&1));
    bf16x8_t Bk[4];
    #pragma unroll
    for(int s=0;s<4;++s)
      Bk[s] = *(const bf16x8_t*)(w2m + ((((wn*4+s)*4+kt)*64 + l)*8));
    #pragma unroll
    for(int a=0;a<3;++a){
      bf16x8_t A = *(const bf16x8_t*)((const unsigned int*)m1f + (((wm*3+a)*4+kt)*256 + pl*4));
      #pragma unroll
      for(int s=0;s<4;++s)
        acc[a][s]=__builtin_amdgcn_mfma_f32_16x16x32_bf16(A, Bk[s], acc[a][s], 0,0,0);
    }
  }

  float b2v[4], w3v[4];
  #pragma unroll
  for(int s=0;s<4;++s){ b2v[s]=b2[(wn*4+s)*16+(l&15)]; w3v[s]=W3[(wn*4+s)*16+(l&15)]; }
  float qv[3][4];
  #pragma unroll
  for(int a=0;a<3;++a)
    #pragma unroll
    for(int r=0;r<4;++r){
      float pj=0.f;
      #pragma unroll
      for(int s=0;s<4;++s) pj += silu(acc[a][s][r]+b2v[s])*w3v[s];
      qv[a][r]=pj;
    }
  #pragma unroll
  for(int d=1;d<16;d<<=1)
    #pragma unroll
    for(int a=0;a<3;++a)
      #pragma unroll
      for(int r=0;r<4;++r)
        qv[a][r] += __shfl_xor(qv[a][r], d);
  if((l&15)==0){
    int quad=l>>4;
    #pragma unroll
    for(int a=0;a<3;++a)
      #pragma unroll
      for(int r=0;r<4;++r)
        redJ[wn][(wm*3+a)*16 + quad*4 + r]=qv[a][r];
  }
  __syncthreads();
  if(tid<Nn){
    float pj=redJ[0][tid]+redJ[1][tid];
    float em=(tid==i)?0.f:nms[tid];
    sjs[tid]=pj*em*rsqrtf(rs[tid]+1e-8f);
  }
  __syncthreads();
  if(w<3){
    int d=w;
    float xi=xs[i][d];
    float s=(xi-xs[l][d])*sjs[l];
    if(l<32) s += (xi-xs[l+64][d])*sjs[l+64];
    s+=__shfl_xor(s,1); s+=__shfl_xor(s,2); s+=__shfl_xor(s,4);
    s+=__shfl_xor(s,8); s+=__shfl_xor(s,16); s+=__shfl_xor(s,32);
    if(l==0) xn[(size_t)(b*Nn+i)*3+d]=(xi+s*(1.f/100.f))*nms[i];
  }
}

// ---------------- per-batch vel stats
__global__ void k_velstat(const float* xf, const float* x0, fp nm, float* vstat){
  __shared__ float sh[128];
  int b=blockIdx.x, tid=threadIdx.x;
  float nmv = (tid<Nn)? nm[b*Nn+tid] : 0.f;
  float vals[4];
  #pragma unroll
  for(int d=0;d<3;++d)
    vals[d] = (tid<Nn)? (xf[(b*Nn+tid)*3+d]-x0[(b*Nn+tid)*3+d])*nmv : 0.f;
  vals[3]=nmv;
  #pragma unroll
  for(int q=0;q<4;++q){
    sh[tid]=vals[q]; __syncthreads();
    for(int s=64;s>0;s>>=1){ if(tid<s) sh[tid]+=sh[tid+s]; __syncthreads(); }
    if(tid==0) vstat[b*4+q]=sh[0];
    __syncthreads();
  }
}

// ---------------- output
__global__ void k_out(const float* h, const float* xf, const float* x0, fp nm,
                      const float* vstat, fp W_out, fp b_out, float* out){
  __shared__ float shh[HD];
  int bn=blockIdx.x, tid=threadIdx.x, b=bn/Nn;
  shh[tid]=h[bn*HD+tid]; __syncthreads();
  float nmv=nm[bn];
  if(tid<3){
    float vel=(xf[bn*3+tid]-x0[bn*3+tid])*nmv;
    float mean=vstat[b*4+tid]/vstat[b*4+3];
    out[bn*(NDIM+HFEAT)+tid]=vel-mean*nmv;
  } else if(tid<3+HFEAT){
    int f=tid-3;
    float acc=b_out[f];
    for(int k=0;k<HD;++k) acc+=shh[k]*W_out[k*FINC+f];
    out[bn*(NDIM+HFEAT)+tid]=acc*nmv;
  }
}

extern "C" void kernel_launch(void* const* d_in, const int* in_sizes, int n_in,
                              void* d_out, int out_size, void* d_ws, size_t ws_size,
                              hipStream_t stream) {
  fp xh   =(fp)d_in[0];
  fp t    =(fp)d_in[1];
  fp nm   =(fp)d_in[2];
  // d_in[3] edge_mask: reproduced exactly as nm_i*nm_j*(i!=j), not read
  fp W_emb=(fp)d_in[4],  b_emb=(fp)d_in[5];
  fp gWe1 =(fp)d_in[6],  gbe1 =(fp)d_in[7];
  fp gWe2 =(fp)d_in[8],  gbe2 =(fp)d_in[9];
  fp gWn1 =(fp)d_in[10], gbn1 =(fp)d_in[11];
  fp gWn2 =(fp)d_in[12], gbn2 =(fp)d_in[13];
  fp eWc1 =(fp)d_in[14], ebc1 =(fp)d_in[15];
  fp eWc2 =(fp)d_in[16], ebc2 =(fp)d_in[17];
  fp eWc3 =(fp)d_in[18];
  fp W_out=(fp)d_in[19], b_out=(fp)d_in[20];

  unsigned short* w1b  = (unsigned short*)d_ws;            // 12*32768
  unsigned short* w2b  = w1b  + (size_t)12*32768;          // 12*16384
  unsigned short* wn1b = w2b  + (size_t)12*16384;          // 8*32768
  unsigned short* wn2b = wn1b + (size_t)8*32768;           // 8*16384
  float* fbase = (float*)(wn2b + (size_t)8*16384);
  float* hA   = fbase;            // BN*HD each
  float* hB   = hA  + BN*HD;
  float* HiA  = hB  + BN*HD;
  float* HjA  = HiA + BN*HD;
  float* HiE  = HjA + BN*HD;
  float* HjE  = HiE + BN*HD;
  float* agg  = HjE + BN*HD;
  float* x0   = agg + BN*HD;      // BN*3
  float* xA   = x0  + BN*3;
  float* xB   = xA  + BN*3;
  float* vstat= xB  + BN*3;       // BSZ*4

  k_prep <<<40,256,0,stream>>>(gWe1, eWc1, gWe2, eWc2, gWn1, gWn2, w1b, w2b, wn1b, wn2b);
  k_embed<<<BN,128,0,stream>>>(xh,t,nm,W_emb,b_emb,hA,x0,xA);
  k_hij  <<<96,256,0,stream>>>(hA, w1b, gbe1, HiA, HjA);
  float *hc=hA, *hn=hB, *xc=xA, *xn=xB;
  for(int l=0;l<4;++l){
    int g=2*l;
    k_pair<<<BN,256,0,stream>>>(HiA,HjA,xc,x0,nm, gWe1+(size_t)g*258*HD,
          w2b+(size_t)g*HD*HD, gbe2+(size_t)g*HD, agg);
    k_nodehij<<<96,256,0,stream>>>(hc,hn,agg,nm,
          wn1b+(size_t)g*32768, gbn1+(size_t)g*HD,
          wn2b+(size_t)g*16384, gbn2+(size_t)g*HD,
          w1b+(size_t)(g+1)*32768, gbe1+(size_t)(g+1)*HD, HiA, HjA,
          nullptr, nullptr, nullptr, nullptr);
    { float* tmp=hc; hc=hn; hn=tmp; }
    g=2*l+1;
    k_pair<<<BN,256,0,stream>>>(HiA,HjA,xc,x0,nm, gWe1+(size_t)g*258*HD,
          w2b+(size_t)g*HD*HD, gbe2+(size_t)g*HD, agg);
    bool last = (l==3);
    k_nodehij<<<96,256,0,stream>>>(hc,hn,agg,nm,
          wn1b+(size_t)g*32768, gbn1+(size_t)g*HD,
          wn2b+(size_t)g*16384, gbn2+(size_t)g*HD,
          w1b+(size_t)(8+l)*32768, ebc1+(size_t)l*HD, HiE, HjE,
          last? nullptr : w1b+(size_t)(g+1)*32768,
          last? nullptr : gbe1+(size_t)(g+1)*HD, HiA, HjA);
    { float* tmp=hc; hc=hn; hn=tmp; }
    k_coord<<<BN,256,0,stream>>>(HiE,HjE,xc,x0,nm, eWc1+(size_t)l*258*HD,
          w2b+(size_t)(8+l)*HD*HD, ebc2+(size_t)l*HD,
          eWc3+(size_t)l*HD, xn);
    { float* tmp=xc; xc=xn; xn=tmp; }
  }
  k_velstat<<<BSZ,128,0,stream>>>(xc,x0,nm,vstat);
  k_out   <<<BN,128,0,stream>>>(hc,xc,x0,nm,vstat,W_out,b_out,(float*)d_out);
}